// Round 11
// baseline (38.721 us; speedup 1.0000x reference)
//
#include <hip/hip_runtime.h>

#define C_CH 128
#define H_IN 80
#define W_IN 80
#define HW 6400
#define OUTS 7
#define NBINS 49   // 7x7

// Weight-chain macros (bit-identical to the passing R5/R7/R8/R10 math).
#define MKR(i)                                                                \
    {                                                                         \
        const float h  = h_##i;                                              \
        const int   hv = (h >= -0.5f) && (h <= (float)H_IN - 0.5f);          \
        nh += hv;                                                            \
        const float hc = fminf(fmaxf(h, 0.0f), (float)H_IN - 1.0f);          \
        const int   h0 = (int)hc;                                            \
        const float lh = hc - (float)h0;                                     \
        const float f  = hv ? 1.0f : 0.0f;                                   \
        const float d0 = (1.0f - lh) * f, d1 = lh * f;                       \
        if ((i) == 0) {                                                      \
            rbase = h0; R0 += d0; R1 += d1;                                  \
        } else {                                                             \
            const int s = h0 - rbase; /* 0..4 */                             \
            R0 += (s == 0) ? d0 : 0.0f;                                      \
            R1 += (s == 1) ? d0 : 0.0f; R1 += (s == 0) ? d1 : 0.0f;          \
            R2 += (s == 2) ? d0 : 0.0f; R2 += (s == 1) ? d1 : 0.0f;          \
            R3 += (s == 3) ? d0 : 0.0f; R3 += (s == 2) ? d1 : 0.0f;          \
            R4 += (s == 4) ? d0 : 0.0f; R4 += (s == 3) ? d1 : 0.0f;          \
            R5 += (s == 4) ? d1 : 0.0f;                                      \
        }                                                                    \
    }

#define MKC(j)                                                                \
    {                                                                         \
        const float w  = w_##j;                                              \
        const int   wv = (w >= -0.5f) && (w <= (float)W_IN - 0.5f);          \
        nw += wv;                                                            \
        const float wc = fminf(fmaxf(w, 0.0f), (float)W_IN - 1.0f);          \
        const int   w0 = (int)wc;                                            \
        const float lw = wc - (float)w0;                                     \
        const float f  = wv ? 1.0f : 0.0f;                                   \
        const float d0 = (1.0f - lw) * f, d1 = lw * f;                       \
        if ((j) == 0) {                                                      \
            cbase = w0; C0 += d0; C1 += d1;                                  \
        } else {                                                             \
            const int s = w0 - cbase;                                        \
            C0 += (s == 0) ? d0 : 0.0f;                                      \
            C1 += (s == 1) ? d0 : 0.0f; C1 += (s == 0) ? d1 : 0.0f;          \
            C2 += (s == 2) ? d0 : 0.0f; C2 += (s == 1) ? d1 : 0.0f;          \
            C3 += (s == 3) ? d0 : 0.0f; C3 += (s == 2) ? d1 : 0.0f;          \
            C4 += (s == 4) ? d0 : 0.0f; C4 += (s == 3) ? d1 : 0.0f;          \
            C5 += (s == 4) ? d1 : 0.0f;                                      \
        }                                                                    \
    }

// ---------------- fused prep: transpose (z<B) + weight packs (z==B) ---------
__global__ __launch_bounds__(256) void prep_kernel(const float* __restrict__ in,
                                                   const float* __restrict__ rois,
                                                   const float* __restrict__ offset,
                                                   float* __restrict__ tout,
                                                   float4* __restrict__ pk,
                                                   int nbins_tot) {
    if (blockIdx.z < gridDim.z - 1) {
        __shared__ float tile[64][33];
        const int b  = blockIdx.z;
        const int c0 = blockIdx.y * 32;
        const int s0 = blockIdx.x * 64;
        const int t  = threadIdx.x;
#pragma unroll
        for (int i = 0; i < 2; i++) {
            const int c  = i * 16 + (t >> 4);
            const int sB = (t & 15) * 4;
            const float4 v = *(const float4*)&in[(size_t)(b * C_CH + c0 + c) * HW + s0 + sB];
            tile[sB + 0][c] = v.x;
            tile[sB + 1][c] = v.y;
            tile[sB + 2][c] = v.z;
            tile[sB + 3][c] = v.w;
        }
        __syncthreads();
#pragma unroll
        for (int i = 0; i < 2; i++) {
            const int s  = i * 32 + (t >> 3);
            const int cq = (t & 7) * 4;
            float4 o;
            o.x = tile[s][cq + 0];
            o.y = tile[s][cq + 1];
            o.z = tile[s][cq + 2];
            o.w = tile[s][cq + 3];
            *(float4*)&tout[(size_t)(b * HW + s0 + s) * C_CH + c0 + cq] = o;
        }
        return;
    }
    // ---- weight blocks ----
    const int stride = gridDim.x * gridDim.y * blockDim.x;
    for (int id = (blockIdx.x * gridDim.y + blockIdx.y) * blockDim.x + threadIdx.x;
         id < nbins_tot; id += stride) {
        const int n   = id / NBINS;
        const int rem = id - n * NBINS;
        const int ph  = rem / OUTS;
        const int pw  = rem - ph * OUTS;
        const int b   = (int)rois[n * 5 + 0];

        float h_0, h_1, h_2, h_3, w_0, w_1, w_2, w_3;
        {
#pragma clang fp contract(off)
            const float sw    = rintf(rois[n * 5 + 1]) * 0.0625f - 0.5f;
            const float sh    = rintf(rois[n * 5 + 2]) * 0.0625f - 0.5f;
            const float ew    = (rintf(rois[n * 5 + 3]) + 1.0f) * 0.0625f - 0.5f;
            const float eh    = (rintf(rois[n * 5 + 4]) + 1.0f) * 0.0625f - 0.5f;
            const float roi_w = fmaxf(ew - sw, 0.1f);
            const float roi_h = fmaxf(eh - sh, 0.1f);
            const float bin_w = roi_w / 7.0f;
            const float bin_h = roi_h / 7.0f;
            const float sub_w = bin_w / 4.0f;
            const float sub_h = bin_h / 4.0f;
            // PART_SIZE == OUT_SIZE == 7 -> part_h == ph, part_w == pw.
            const float tx = offset[(n * 2 + 0) * NBINS + ph * OUTS + pw] * 0.1f;
            const float ty = offset[(n * 2 + 1) * NBINS + ph * OUTS + pw] * 0.1f;
            const float wstart = (float)pw * bin_w + sw + tx * roi_w;
            const float hstart = (float)ph * bin_h + sh + ty * roi_h;
            h_0 = hstart;                 w_0 = wstart;
            h_1 = hstart + sub_h;         w_1 = wstart + sub_w;
            h_2 = hstart + 2.0f * sub_h;  w_2 = wstart + 2.0f * sub_w;
            h_3 = hstart + 3.0f * sub_h;  w_3 = wstart + 3.0f * sub_w;
        }

        int   nh = 0, nw = 0, rbase = 0, cbase = 0;
        float R0 = 0.f, R1 = 0.f, R2 = 0.f, R3 = 0.f, R4 = 0.f, R5 = 0.f;
        float C0 = 0.f, C1 = 0.f, C2 = 0.f, C3 = 0.f, C4 = 0.f, C5 = 0.f;
        MKR(0) MKR(1) MKR(2) MKR(3)
        MKC(0) MKC(1) MKC(2) MKC(3)

        const int   cnt = nh * nw;
        const float inv = cnt > 0 ? 1.0f / (float)cnt : 0.0f;
        pk[id * 4 + 0] = make_float4(R0, R1, R2, R3);
        pk[id * 4 + 1] = make_float4(R4, R5, C0, C1);
        pk[id * 4 + 2] = make_float4(C2, C3, C4, C5);
        pk[id * 4 + 3] = make_float4(__int_as_float(rbase), __int_as_float(cbase),
                                     inv, __int_as_float(b * HW));
    }
}

// ------- pure-gather droi: grid (N,7), ONE BIN PER WAVE, batched loads ------
// R11 isolates the grid/TLP variable: R8's (N,7) 448-thr one-bin-per-wave
// structure (25088 waves, up to 28 waves/CU) + R10's branchless batched
// 18-load gather. No per-wave loop, no dedup selects (unconditional clamped
// addresses; zero weights kill out-of-window terms exactly).

#define LD3(r) const float4 vA##r = d4[ro##r + coff0];                        \
               const float4 vB##r = d4[ro##r + coff1];                        \
               const float4 vC##r = d4[ro##r + coff2];

#define ACC3(r)                                                               \
    {                                                                         \
        const float g0 = R##r * ws0, g1 = R##r * ws1, g2 = R##r * ws2;        \
        a0 += g0 * vA##r.x + g1 * vB##r.x + g2 * vC##r.x;                     \
        a1 += g0 * vA##r.y + g1 * vB##r.y + g2 * vC##r.y;                     \
        a2 += g0 * vA##r.z + g1 * vB##r.z + g2 * vC##r.z;                     \
        a3 += g0 * vA##r.w + g1 * vB##r.w + g2 * vC##r.w;                     \
    }

#define ROFF(r) const size_t ro##r =                                          \
    (size_t)(pixbase + min(rbase + (r), H_IN - 1) * W_IN) * 32;

__global__ __launch_bounds__(448) void droi_kernel10(const float4* __restrict__ d4,
                                                     const float4* __restrict__ pk,
                                                     float* __restrict__ out) {
    __shared__ float lds[C_CH * OUTS];   // [c][pw], 3.5 KB
    const int n    = blockIdx.x;
    const int ph   = blockIdx.y;
    const int tid  = threadIdx.x;
    const int pw   = tid >> 6;
    const int lane = tid & 63;
    const int half = lane >> 5;          // window-column parity
    const int cq   = lane & 31;          // channel quad

    const float4* q  = pk + (((size_t)n * NBINS + ph * OUTS + pw) << 2);
    const float4  q0 = q[0], q1 = q[1], q2 = q[2], q3 = q[3];
    const float R0 = q0.x, R1 = q0.y, R2 = q0.z, R3 = q0.w, R4 = q1.x, R5 = q1.y;
    const float C0 = q1.z, C1 = q1.w, C2 = q2.x, C3 = q2.y, C4 = q2.z, C5 = q2.w;
    const int   rbase   = __float_as_int(q3.x);
    const int   cbase   = __float_as_int(q3.y);
    const float inv     = q3.z;
    const int   pixbase = __float_as_int(q3.w);

    const int coff0 = min(cbase + 0 + half, W_IN - 1) * 32 + cq;
    const int coff1 = min(cbase + 2 + half, W_IN - 1) * 32 + cq;
    const int coff2 = min(cbase + 4 + half, W_IN - 1) * 32 + cq;
    const float ws0 = half ? C1 : C0;
    const float ws1 = half ? C3 : C2;
    const float ws2 = half ? C5 : C4;

    ROFF(0) ROFF(1) ROFF(2) ROFF(3) ROFF(4) ROFF(5)

    // 18 unconditional loads in one basic block -> single latency exposure.
    LD3(0) LD3(1) LD3(2) LD3(3) LD3(4) LD3(5)

    float a0 = 0.f, a1 = 0.f, a2 = 0.f, a3 = 0.f;
    ACC3(0) ACC3(1) ACC3(2) ACC3(3) ACC3(4) ACC3(5)

    // fold the two column-parity halves together
    a0 += __shfl_xor(a0, 32, 64);
    a1 += __shfl_xor(a1, 32, 64);
    a2 += __shfl_xor(a2, 32, 64);
    a3 += __shfl_xor(a3, 32, 64);

    if (lane < 32) {
        const int c = 4 * cq;
        lds[(c + 0) * OUTS + pw] = a0 * inv;
        lds[(c + 1) * OUTS + pw] = a1 * inv;
        lds[(c + 2) * OUTS + pw] = a2 * inv;
        lds[(c + 3) * OUTS + pw] = a3 * inv;
    }
    __syncthreads();

    // out[n, c, ph, pw]: 896 floats per block, staged -> semi-coalesced.
    const size_t obase = (size_t)n * (C_CH * NBINS) + (size_t)ph * OUTS;
    for (int f = tid; f < C_CH * OUTS; f += 448) {
        const int c = f / OUTS, k = f - c * OUTS;
        out[obase + (size_t)c * NBINS + k] = lds[f];
    }
}

// ---------------- fallback (no workspace): CHW gather, known-correct ---------
__global__ __launch_bounds__(512) void droi_fallback(const float* __restrict__ data,
                                                     const float* __restrict__ rois,
                                                     const float* __restrict__ offset,
                                                     float* __restrict__ out) {
#pragma clang fp contract(off)
    __shared__ float lds[C_CH * NBINS];
    const int n    = blockIdx.x;
    const int tid  = threadIdx.x;
    const int wave = tid >> 6;
    const int lane = tid & 63;

    const int   b     = (int)rois[n * 5 + 0];
    const float sw    = rintf(rois[n * 5 + 1]) * 0.0625f - 0.5f;
    const float sh    = rintf(rois[n * 5 + 2]) * 0.0625f - 0.5f;
    const float ew    = (rintf(rois[n * 5 + 3]) + 1.0f) * 0.0625f - 0.5f;
    const float eh    = (rintf(rois[n * 5 + 4]) + 1.0f) * 0.0625f - 0.5f;
    const float roi_w = fmaxf(ew - sw, 0.1f);
    const float roi_h = fmaxf(eh - sh, 0.1f);
    const float bin_w = roi_w / 7.0f, bin_h = roi_h / 7.0f;
    const float sub_w = bin_w / 4.0f, sub_h = bin_h / 4.0f;

    for (int bin = wave; bin < NBINS; bin += 8) {
        const int ph = bin / 7;
        const int pw = bin - ph * 7;
        const float tx = offset[((n * 2 + 0) * 7 + ph) * 7 + pw] * 0.1f;
        const float ty = offset[((n * 2 + 1) * 7 + ph) * 7 + pw] * 0.1f;
        const float wstart = (float)pw * bin_w + sw + tx * roi_w;
        const float hstart = (float)ph * bin_h + sh + ty * roi_h;
        float s0 = 0.0f, s1 = 0.0f;
        int   cnt = 0;
        for (int ih = 0; ih < 4; ih++) {
            const float h = hstart + (float)ih * sub_h;
            if (h < -0.5f || h > (float)H_IN - 0.5f) continue;
            for (int iw = 0; iw < 4; iw++) {
                const float w = wstart + (float)iw * sub_w;
                if (w < -0.5f || w > (float)W_IN - 0.5f) continue;
                cnt++;
                const float hc = fminf(fmaxf(h, 0.0f), (float)H_IN - 1.0f);
                const float wc = fminf(fmaxf(w, 0.0f), (float)W_IN - 1.0f);
                const int h0 = (int)floorf(hc), w0 = (int)floorf(wc);
                const int h1 = min(h0 + 1, H_IN - 1), w1 = min(w0 + 1, W_IN - 1);
                const float lh = hc - (float)h0, lw = wc - (float)w0;
                const float w00 = (1.0f - lh) * (1.0f - lw), w01 = (1.0f - lh) * lw;
                const float w10 = lh * (1.0f - lw), w11 = lh * lw;
                const float* pb  = data + (size_t)b * C_CH * HW;
                const int i00 = h0 * W_IN + w0, i01 = h0 * W_IN + w1;
                const int i10 = h1 * W_IN + w0, i11 = h1 * W_IN + w1;
                const float* pc0 = pb + (size_t)lane * HW;
                const float* pc1 = pb + (size_t)(lane + 64) * HW;
                s0 += w00 * pc0[i00] + w01 * pc0[i01] + w10 * pc0[i10] + w11 * pc0[i11];
                s1 += w00 * pc1[i00] + w01 * pc1[i01] + w10 * pc1[i10] + w11 * pc1[i11];
            }
        }
        lds[lane * NBINS + bin]        = cnt > 0 ? s0 / (float)cnt : 0.0f;
        lds[(lane + 64) * NBINS + bin] = cnt > 0 ? s1 / (float)cnt : 0.0f;
    }
    __syncthreads();
    const size_t obase = (size_t)n * (C_CH * NBINS);
    for (int f = tid; f < C_CH * NBINS; f += 512)
        out[obase + f] = lds[f];
}

extern "C" void kernel_launch(void* const* d_in, const int* in_sizes, int n_in,
                              void* d_out, int out_size, void* d_ws, size_t ws_size,
                              hipStream_t stream) {
    const float* data   = (const float*)d_in[0];
    const float* rois   = (const float*)d_in[1];
    const float* offset = (const float*)d_in[2];
    float*       outp   = (float*)d_out;

    const int N = in_sizes[1] / 5;                 // 512
    const int B = in_sizes[0] / (C_CH * HW);       // 2
    const size_t tfloats = (size_t)B * HW * C_CH;                // NHWC tensor
    const size_t need    = tfloats * sizeof(float) + (size_t)N * NBINS * 64;

    if (ws_size >= need) {
        float*  tws = (float*)d_ws;
        float4* pk  = (float4*)((char*)d_ws + tfloats * sizeof(float));
        dim3 gp(HW / 64, C_CH / 32, B + 1), bp(256);
        prep_kernel<<<gp, bp, 0, stream>>>(data, rois, offset, tws, pk, N * NBINS);
        dim3 gd(N, OUTS);
        droi_kernel10<<<gd, 448, 0, stream>>>((const float4*)tws, pk, outp);
    } else {
        droi_fallback<<<N, 512, 0, stream>>>(data, rois, offset, outp);
    }
}

// Round 12
// 35.966 us; speedup vs baseline: 1.0766x; 1.0766x over previous
//
#include <hip/hip_runtime.h>

#define C_CH 128
#define H_IN 80
#define W_IN 80
#define HW 6400
#define OUTS 7
#define NBINS 49   // 7x7

// Weight-chain macros (bit-identical to the passing R5/R7/R8/R10 math).
#define MKR(i)                                                                \
    {                                                                         \
        const float h  = h_##i;                                              \
        const int   hv = (h >= -0.5f) && (h <= (float)H_IN - 0.5f);          \
        nh += hv;                                                            \
        const float hc = fminf(fmaxf(h, 0.0f), (float)H_IN - 1.0f);          \
        const int   h0 = (int)hc;                                            \
        const float lh = hc - (float)h0;                                     \
        const float f  = hv ? 1.0f : 0.0f;                                   \
        const float d0 = (1.0f - lh) * f, d1 = lh * f;                       \
        if ((i) == 0) {                                                      \
            rbase = h0; R0 += d0; R1 += d1;                                  \
        } else {                                                             \
            const int s = h0 - rbase; /* 0..4 */                             \
            R0 += (s == 0) ? d0 : 0.0f;                                      \
            R1 += (s == 1) ? d0 : 0.0f; R1 += (s == 0) ? d1 : 0.0f;          \
            R2 += (s == 2) ? d0 : 0.0f; R2 += (s == 1) ? d1 : 0.0f;          \
            R3 += (s == 3) ? d0 : 0.0f; R3 += (s == 2) ? d1 : 0.0f;          \
            R4 += (s == 4) ? d0 : 0.0f; R4 += (s == 3) ? d1 : 0.0f;          \
            R5 += (s == 4) ? d1 : 0.0f;                                      \
        }                                                                    \
    }

#define MKC(j)                                                                \
    {                                                                         \
        const float w  = w_##j;                                              \
        const int   wv = (w >= -0.5f) && (w <= (float)W_IN - 0.5f);          \
        nw += wv;                                                            \
        const float wc = fminf(fmaxf(w, 0.0f), (float)W_IN - 1.0f);          \
        const int   w0 = (int)wc;                                            \
        const float lw = wc - (float)w0;                                     \
        const float f  = wv ? 1.0f : 0.0f;                                   \
        const float d0 = (1.0f - lw) * f, d1 = lw * f;                       \
        if ((j) == 0) {                                                      \
            cbase = w0; C0 += d0; C1 += d1;                                  \
        } else {                                                             \
            const int s = w0 - cbase;                                        \
            C0 += (s == 0) ? d0 : 0.0f;                                      \
            C1 += (s == 1) ? d0 : 0.0f; C1 += (s == 0) ? d1 : 0.0f;          \
            C2 += (s == 2) ? d0 : 0.0f; C2 += (s == 1) ? d1 : 0.0f;          \
            C3 += (s == 3) ? d0 : 0.0f; C3 += (s == 2) ? d1 : 0.0f;          \
            C4 += (s == 4) ? d0 : 0.0f; C4 += (s == 3) ? d1 : 0.0f;          \
            C5 += (s == 4) ? d1 : 0.0f;                                      \
        }                                                                    \
    }

// ---------------- fused prep: transpose (z<B) + weight packs (z==B) ---------
__global__ __launch_bounds__(256) void prep_kernel(const float* __restrict__ in,
                                                   const float* __restrict__ rois,
                                                   const float* __restrict__ offset,
                                                   float* __restrict__ tout,
                                                   float4* __restrict__ pk,
                                                   int nbins_tot) {
    if (blockIdx.z < gridDim.z - 1) {
        __shared__ float tile[64][33];
        const int b  = blockIdx.z;
        const int c0 = blockIdx.y * 32;
        const int s0 = blockIdx.x * 64;
        const int t  = threadIdx.x;
#pragma unroll
        for (int i = 0; i < 2; i++) {
            const int c  = i * 16 + (t >> 4);
            const int sB = (t & 15) * 4;
            const float4 v = *(const float4*)&in[(size_t)(b * C_CH + c0 + c) * HW + s0 + sB];
            tile[sB + 0][c] = v.x;
            tile[sB + 1][c] = v.y;
            tile[sB + 2][c] = v.z;
            tile[sB + 3][c] = v.w;
        }
        __syncthreads();
#pragma unroll
        for (int i = 0; i < 2; i++) {
            const int s  = i * 32 + (t >> 3);
            const int cq = (t & 7) * 4;
            float4 o;
            o.x = tile[s][cq + 0];
            o.y = tile[s][cq + 1];
            o.z = tile[s][cq + 2];
            o.w = tile[s][cq + 3];
            *(float4*)&tout[(size_t)(b * HW + s0 + s) * C_CH + c0 + cq] = o;
        }
        return;
    }
    // ---- weight blocks ----
    const int stride = gridDim.x * gridDim.y * blockDim.x;
    for (int id = (blockIdx.x * gridDim.y + blockIdx.y) * blockDim.x + threadIdx.x;
         id < nbins_tot; id += stride) {
        const int n   = id / NBINS;
        const int rem = id - n * NBINS;
        const int ph  = rem / OUTS;
        const int pw  = rem - ph * OUTS;
        const int b   = (int)rois[n * 5 + 0];

        float h_0, h_1, h_2, h_3, w_0, w_1, w_2, w_3;
        {
#pragma clang fp contract(off)
            const float sw    = rintf(rois[n * 5 + 1]) * 0.0625f - 0.5f;
            const float sh    = rintf(rois[n * 5 + 2]) * 0.0625f - 0.5f;
            const float ew    = (rintf(rois[n * 5 + 3]) + 1.0f) * 0.0625f - 0.5f;
            const float eh    = (rintf(rois[n * 5 + 4]) + 1.0f) * 0.0625f - 0.5f;
            const float roi_w = fmaxf(ew - sw, 0.1f);
            const float roi_h = fmaxf(eh - sh, 0.1f);
            const float bin_w = roi_w / 7.0f;
            const float bin_h = roi_h / 7.0f;
            const float sub_w = bin_w / 4.0f;
            const float sub_h = bin_h / 4.0f;
            // PART_SIZE == OUT_SIZE == 7 -> part_h == ph, part_w == pw.
            const float tx = offset[(n * 2 + 0) * NBINS + ph * OUTS + pw] * 0.1f;
            const float ty = offset[(n * 2 + 1) * NBINS + ph * OUTS + pw] * 0.1f;
            const float wstart = (float)pw * bin_w + sw + tx * roi_w;
            const float hstart = (float)ph * bin_h + sh + ty * roi_h;
            h_0 = hstart;                 w_0 = wstart;
            h_1 = hstart + sub_h;         w_1 = wstart + sub_w;
            h_2 = hstart + 2.0f * sub_h;  w_2 = wstart + 2.0f * sub_w;
            h_3 = hstart + 3.0f * sub_h;  w_3 = wstart + 3.0f * sub_w;
        }

        int   nh = 0, nw = 0, rbase = 0, cbase = 0;
        float R0 = 0.f, R1 = 0.f, R2 = 0.f, R3 = 0.f, R4 = 0.f, R5 = 0.f;
        float C0 = 0.f, C1 = 0.f, C2 = 0.f, C3 = 0.f, C4 = 0.f, C5 = 0.f;
        MKR(0) MKR(1) MKR(2) MKR(3)
        MKC(0) MKC(1) MKC(2) MKC(3)

        const int   cnt = nh * nw;
        const float inv = cnt > 0 ? 1.0f / (float)cnt : 0.0f;
        pk[id * 4 + 0] = make_float4(R0, R1, R2, R3);
        pk[id * 4 + 1] = make_float4(R4, R5, C0, C1);
        pk[id * 4 + 2] = make_float4(C2, C3, C4, C5);
        pk[id * 4 + 3] = make_float4(__int_as_float(rbase), __int_as_float(cbase),
                                     inv, __int_as_float(b * HW));
    }
}

// ---------------- pure-gather deformable RoI pool, BRANCHLESS batched -------
// Best measured variant (R10, 36.1 us). Grid N (512 blocks, 448 thr), wave ==
// ph, rolled loop over pw. Per bin all 18 dwordx4 loads sit in ONE basic
// block (batched issue, single latency exposure); inactive rows/pairs dedup
// to already-loaded addresses (L1 hit) with exactly-zero weights. Full
// 128x49 roi staged in 25 KB LDS, written fully coalesced (exact 25 KB/roi).

#define RDEDUP(r) const int rr##r = (R##r != 0.0f) ? min(rbase + (r), H_IN - 1) : rbase; \
                  const size_t ro##r = (size_t)(pixbase + rr##r * W_IN) * 32;

#define LD3(r) const float4 vA##r = d4[ro##r + coff0];                        \
               const float4 vB##r = d4[ro##r + coff1];                        \
               const float4 vC##r = d4[ro##r + coff2];

#define ACC3(r)                                                               \
    {                                                                         \
        const float g0 = R##r * ws0, g1 = R##r * ws1, g2 = R##r * ws2;        \
        a0 += g0 * vA##r.x + g1 * vB##r.x + g2 * vC##r.x;                     \
        a1 += g0 * vA##r.y + g1 * vB##r.y + g2 * vC##r.y;                     \
        a2 += g0 * vA##r.z + g1 * vB##r.z + g2 * vC##r.z;                     \
        a3 += g0 * vA##r.w + g1 * vB##r.w + g2 * vC##r.w;                     \
    }

__global__ __launch_bounds__(448, 4) void droi_kernel9(const float4* __restrict__ d4,
                                                       const float4* __restrict__ pk,
                                                       float* __restrict__ out) {
    __shared__ float lds[C_CH * NBINS];   // 25088 B, full roi output [c][bin]
    const int n    = blockIdx.x;
    const int ph   = threadIdx.x >> 6;   // wave id == output row
    const int lane = threadIdx.x & 63;
    const int half = lane >> 5;          // window-column parity
    const int cq   = lane & 31;          // channel quad

#pragma unroll 1
    for (int pw = 0; pw < OUTS; pw++) {
        const float4* q  = pk + (((size_t)n * NBINS + ph * OUTS + pw) << 2);
        const float4  q0 = q[0], q1 = q[1], q2 = q[2], q3 = q[3];
        const float R0 = q0.x, R1 = q0.y, R2 = q0.z, R3 = q0.w, R4 = q1.x, R5 = q1.y;
        const float C0 = q1.z, C1 = q1.w, C2 = q2.x, C3 = q2.y, C4 = q2.z, C5 = q2.w;
        const int   rbase   = __float_as_int(q3.x);
        const int   cbase   = __float_as_int(q3.y);
        const float inv     = q3.z;
        const int   pixbase = __float_as_int(q3.w);

        const int c0o = min(cbase + 0 + half, W_IN - 1) * 32 + cq;
        const int c1o = min(cbase + 2 + half, W_IN - 1) * 32 + cq;
        const int c2o = min(cbase + 4 + half, W_IN - 1) * 32 + cq;
        const bool p1 = (C2 + C3) > 0.0f;   // weights are >= 0
        const bool p2 = (C4 + C5) > 0.0f;
        const int coff0 = c0o;
        const int coff1 = p1 ? c1o : c0o;   // dedup -> L1 hit, weight 0
        const int coff2 = p2 ? c2o : c0o;
        const float ws0 = half ? C1 : C0;
        const float ws1 = half ? C3 : C2;
        const float ws2 = half ? C5 : C4;

        RDEDUP(0) RDEDUP(1) RDEDUP(2) RDEDUP(3) RDEDUP(4) RDEDUP(5)

        // 18 unconditional loads, one basic block -> batched issue.
        LD3(0) LD3(1) LD3(2) LD3(3) LD3(4) LD3(5)

        float a0 = 0.f, a1 = 0.f, a2 = 0.f, a3 = 0.f;
        ACC3(0) ACC3(1) ACC3(2) ACC3(3) ACC3(4) ACC3(5)

        // fold the two column-parity halves together
        a0 += __shfl_xor(a0, 32, 64);
        a1 += __shfl_xor(a1, 32, 64);
        a2 += __shfl_xor(a2, 32, 64);
        a3 += __shfl_xor(a3, 32, 64);

        if (lane < 32) {
            const int c   = 4 * cq;
            const int bin = ph * OUTS + pw;
            lds[(c + 0) * NBINS + bin] = a0 * inv;
            lds[(c + 1) * NBINS + bin] = a1 * inv;
            lds[(c + 2) * NBINS + bin] = a2 * inv;
            lds[(c + 3) * NBINS + bin] = a3 * inv;
        }
    }
    __syncthreads();

    // out[n, :, :, :]: 6272 floats = 1568 float4, fully coalesced.
    float4*       o4 = (float4*)(out + (size_t)n * (C_CH * NBINS));
    const float4* l4 = (const float4*)lds;
    for (int f = threadIdx.x; f < (C_CH * NBINS) / 4; f += 448)
        o4[f] = l4[f];
}

// ---------------- fallback (no workspace): CHW gather, known-correct ---------
__global__ __launch_bounds__(512) void droi_fallback(const float* __restrict__ data,
                                                     const float* __restrict__ rois,
                                                     const float* __restrict__ offset,
                                                     float* __restrict__ out) {
#pragma clang fp contract(off)
    __shared__ float lds[C_CH * NBINS];
    const int n    = blockIdx.x;
    const int tid  = threadIdx.x;
    const int wave = tid >> 6;
    const int lane = tid & 63;

    const int   b     = (int)rois[n * 5 + 0];
    const float sw    = rintf(rois[n * 5 + 1]) * 0.0625f - 0.5f;
    const float sh    = rintf(rois[n * 5 + 2]) * 0.0625f - 0.5f;
    const float ew    = (rintf(rois[n * 5 + 3]) + 1.0f) * 0.0625f - 0.5f;
    const float eh    = (rintf(rois[n * 5 + 4]) + 1.0f) * 0.0625f - 0.5f;
    const float roi_w = fmaxf(ew - sw, 0.1f);
    const float roi_h = fmaxf(eh - sh, 0.1f);
    const float bin_w = roi_w / 7.0f, bin_h = roi_h / 7.0f;
    const float sub_w = bin_w / 4.0f, sub_h = bin_h / 4.0f;

    for (int bin = wave; bin < NBINS; bin += 8) {
        const int ph = bin / 7;
        const int pw = bin - ph * 7;
        const float tx = offset[((n * 2 + 0) * 7 + ph) * 7 + pw] * 0.1f;
        const float ty = offset[((n * 2 + 1) * 7 + ph) * 7 + pw] * 0.1f;
        const float wstart = (float)pw * bin_w + sw + tx * roi_w;
        const float hstart = (float)ph * bin_h + sh + ty * roi_h;
        float s0 = 0.0f, s1 = 0.0f;
        int   cnt = 0;
        for (int ih = 0; ih < 4; ih++) {
            const float h = hstart + (float)ih * sub_h;
            if (h < -0.5f || h > (float)H_IN - 0.5f) continue;
            for (int iw = 0; iw < 4; iw++) {
                const float w = wstart + (float)iw * sub_w;
                if (w < -0.5f || w > (float)W_IN - 0.5f) continue;
                cnt++;
                const float hc = fminf(fmaxf(h, 0.0f), (float)H_IN - 1.0f);
                const float wc = fminf(fmaxf(w, 0.0f), (float)W_IN - 1.0f);
                const int h0 = (int)floorf(hc), w0 = (int)floorf(wc);
                const int h1 = min(h0 + 1, H_IN - 1), w1 = min(w0 + 1, W_IN - 1);
                const float lh = hc - (float)h0, lw = wc - (float)w0;
                const float w00 = (1.0f - lh) * (1.0f - lw), w01 = (1.0f - lh) * lw;
                const float w10 = lh * (1.0f - lw), w11 = lh * lw;
                const float* pb  = data + (size_t)b * C_CH * HW;
                const int i00 = h0 * W_IN + w0, i01 = h0 * W_IN + w1;
                const int i10 = h1 * W_IN + w0, i11 = h1 * W_IN + w1;
                const float* pc0 = pb + (size_t)lane * HW;
                const float* pc1 = pb + (size_t)(lane + 64) * HW;
                s0 += w00 * pc0[i00] + w01 * pc0[i01] + w10 * pc0[i10] + w11 * pc0[i11];
                s1 += w00 * pc1[i00] + w01 * pc1[i01] + w10 * pc1[i10] + w11 * pc1[i11];
            }
        }
        lds[lane * NBINS + bin]        = cnt > 0 ? s0 / (float)cnt : 0.0f;
        lds[(lane + 64) * NBINS + bin] = cnt > 0 ? s1 / (float)cnt : 0.0f;
    }
    __syncthreads();
    const size_t obase = (size_t)n * (C_CH * NBINS);
    for (int f = tid; f < C_CH * NBINS; f += 512)
        out[obase + f] = lds[f];
}

extern "C" void kernel_launch(void* const* d_in, const int* in_sizes, int n_in,
                              void* d_out, int out_size, void* d_ws, size_t ws_size,
                              hipStream_t stream) {
    const float* data   = (const float*)d_in[0];
    const float* rois   = (const float*)d_in[1];
    const float* offset = (const float*)d_in[2];
    float*       outp   = (float*)d_out;

    const int N = in_sizes[1] / 5;                 // 512
    const int B = in_sizes[0] / (C_CH * HW);       // 2
    const size_t tfloats = (size_t)B * HW * C_CH;                // NHWC tensor
    const size_t need    = tfloats * sizeof(float) + (size_t)N * NBINS * 64;

    if (ws_size >= need) {
        float*  tws = (float*)d_ws;
        float4* pk  = (float4*)((char*)d_ws + tfloats * sizeof(float));
        dim3 gp(HW / 64, C_CH / 32, B + 1), bp(256);
        prep_kernel<<<gp, bp, 0, stream>>>(data, rois, offset, tws, pk, N * NBINS);
        droi_kernel9<<<N, 448, 0, stream>>>((const float4*)tws, pk, outp);
    } else {
        droi_fallback<<<N, 512, 0, stream>>>(data, rois, offset, outp);
    }
}